// Round 6
// baseline (889.702 us; speedup 1.0000x reference)
//
#include <hip/hip_runtime.h>
#include <hip/hip_bf16.h>

#define T_  4
#define B_  32
#define C_  512
#define CV_ 2048
#define N_  256
#define NH_ 8
#define DH_ 64
#define DV_ 256

typedef __bf16 bf16_t;
typedef __bf16 bf16x8 __attribute__((ext_vector_type(8)));
typedef float  f32x4  __attribute__((ext_vector_type(4)));
typedef unsigned char u8x8 __attribute__((ext_vector_type(8)));

#if defined(__has_builtin)
# if __has_builtin(__builtin_amdgcn_global_load_lds)
#  define USE_GLL 1
# endif
#endif

__device__ __forceinline__ f32x4 mfma16(bf16x8 a, bf16x8 b, f32x4 c) {
  return __builtin_amdgcn_mfma_f32_16x16x32_bf16(a, b, c, 0, 0, 0);
}

// s = round(clip(u,0,8)); rintf = round-half-even, matching jnp.round/np.round
__device__ __forceinline__ float quant_step(float u) {
  return rintf(fminf(fmaxf(u, 0.0f), 8.0f));
}

// uchar8 (spike ints 0..8) -> bf16x8 exact integer values
__device__ __forceinline__ bf16x8 cvt8(u8x8 v) {
  bf16x8 r;
#pragma unroll
  for (int j = 0; j < 8; ++j) r[j] = (bf16_t)(float)(unsigned int)v[j];
  return r;
}

// Async 16B/lane global->LDS stage. lbase must be wave-uniform; HW dest =
// lbase + lane*16 (m104/m108). Fallback: VGPR round-trip.
__device__ __forceinline__ void stage16(const void* g, void* lbase, int lane) {
#ifdef USE_GLL
  __builtin_amdgcn_global_load_lds(
      (const __attribute__((address_space(1))) void*)g,
      (__attribute__((address_space(3))) void*)lbase, 16, 0, 0);
#else
  *(uint4*)((char*)lbase + lane * 16) = *(const uint4*)g;
#endif
}

// ---------------- Kernel 0: split f32 weights into bf16 hi + lo ----------------
__global__ __launch_bounds__(256) void k0_split(const float* __restrict__ src,
                                                bf16_t* __restrict__ hi,
                                                bf16_t* __restrict__ lo, int n8) {
  int i = blockIdx.x * 256 + threadIdx.x;
  if (i >= n8) return;
  const float* s = src + (size_t)i * 8;
  bf16x8 h, l;
#pragma unroll
  for (int j = 0; j < 8; ++j) {
    float w = s[j];
    __bf16 hh = (__bf16)w;
    h[j] = hh;
    l[j] = (__bf16)(w - (float)hh);   // near-exact residual
  }
  *(bf16x8*)(hi + (size_t)i * 8) = h;
  *(bf16x8*)(lo + (size_t)i * 8) = l;
}

// ---------------- Kernel 1: xs = sfa(x) -> xsT [t,b,n,c] u8 spike ints ------------
// LDS tile transpose: coalesced f32 reads (n-contig) and u8 writes (c-contig).
__global__ __launch_bounds__(256) void k1_sfa_x(const float* __restrict__ x,
                                                unsigned char* __restrict__ xsT) {
  __shared__ unsigned char tile[64 * 80];        // [n][c], pad 80 (16-aligned rows)
  int bt = blockIdx.x;                            // c-tile = bt>>2, n-tile = bt&3
  int b  = blockIdx.y;
  int tid = threadIdx.x;
  int c0 = (bt >> 2) * 64, n0 = (bt & 3) * 64;
  int cl = tid >> 2, nc = (tid & 3) * 16;        // reader role: c-row, 16-n chunk
  int nl = tid >> 2, cj = (tid & 3) * 16;        // writer role: n-row, 16-c chunk

  float h[16];
#pragma unroll
  for (int j = 0; j < 16; ++j) h[j] = 0.0f;

  for (int t = 0; t < T_; ++t) {
    const float* xp = x + ((size_t)(t * B_ + b) * C_ + c0 + cl) * N_ + n0 + nc;
    f32x4 xv[4];
#pragma unroll
    for (int j = 0; j < 4; ++j) xv[j] = *(const f32x4*)(xp + j * 4);
    if (t) __syncthreads();                      // prior reads done before overwrite
#pragma unroll
    for (int j = 0; j < 16; ++j) {
      float u = __fadd_rn(h[j], xv[j >> 2][j & 3]);  // reference scan op order
      float s = quant_step(u);
      h[j] = __fsub_rn(u, s);                    // exact
      tile[(nc + j) * 80 + cl] = (unsigned char)s;
    }
    __syncthreads();
    uint4 o = *(const uint4*)&tile[nl * 80 + cj];
    *(uint4*)(xsT + ((size_t)(t * B_ + b) * N_ + n0 + nl) * C_ + c0 + cj) = o;
  }
}

// ---------------- Kernel 2: q|k|v = sfa(conv_bn(xs, W)), LDS-staged MFMA ----------
// Block: 64 co x 256 n, one b; t-loop inside (scan state in regs). BK=64.
// u8 xs staged 16KB/chunk; weights hi/lo 16KB. XOR swizzles keep global_load_lds
// lane-contiguous and LDS reads <=2-way-conflicted.
__global__ __launch_bounds__(256) void k2_qkv(
    const unsigned char* __restrict__ xsT,
    const bf16_t* __restrict__ w_hi, const bf16_t* __restrict__ w_lo,
    const float* __restrict__ q_scale, const float* __restrict__ q_bias,
    const float* __restrict__ k_scale, const float* __restrict__ k_bias,
    const float* __restrict__ v_scale, const float* __restrict__ v_bias,
    unsigned char* __restrict__ q_s8, unsigned char* __restrict__ k_s8,
    unsigned char* __restrict__ v_s8) {
  __shared__ __align__(16) unsigned char xs_l[256 * 64];  // 16 KB
  __shared__ __align__(16) bf16_t whi_l[64 * 64];         //  8 KB
  __shared__ __align__(16) bf16_t wlo_l[64 * 64];         //  8 KB

  int ct = blockIdx.x;                 // 0..47: 8 q, 8 k, 32 v co-tiles
  int b  = blockIdx.y;
  int tid = threadIdx.x;
  int w = tid >> 6, lane = tid & 63, quad = lane >> 4, l16 = lane & 15;
  int nl4 = lane >> 2, m4 = lane & 3;  // u8 staging roles (64B rows, 4 granules)
  int nl8 = lane >> 3, m8 = lane & 7;  // bf16 staging roles (128B rows, 8 granules)

  int mode, co_out;
  const float *scp, *bip;
  if (ct < 8)       { mode = 0; co_out = ct * 64;        scp = q_scale; bip = q_bias; }
  else if (ct < 16) { mode = 1; co_out = (ct - 8) * 64;  scp = k_scale; bip = k_bias; }
  else              { mode = 2; co_out = (ct - 16) * 64; scp = v_scale; bip = v_bias; }

  const bf16_t* wrow = w_hi + (size_t)ct * 64 * C_;  // combined rows: ct*64
  const bf16_t* lrow = w_lo + (size_t)ct * 64 * C_;

  float hst[4][4][4];
#pragma unroll
  for (int mt = 0; mt < 4; ++mt)
#pragma unroll
    for (int nt = 0; nt < 4; ++nt)
#pragma unroll
      for (int r = 0; r < 4; ++r) hst[mt][nt][r] = 0.0f;

  for (int t = 0; t < T_; ++t) {
    const unsigned char* xrow = xsT + (size_t)(t * B_ + b) * N_ * C_;
    f32x4 acc[4][4];
#pragma unroll
    for (int mt = 0; mt < 4; ++mt)
#pragma unroll
      for (int nt = 0; nt < 4; ++nt) acc[mt][nt] = (f32x4){0.f, 0.f, 0.f, 0.f};

    for (int kc = 0; kc < 8; ++kc) {             // K = 512, BK = 64
      int c0 = kc * 64;
      __syncthreads();                            // prior compute done
      // stage xs chunk [256n x 64c] u8: wave w rows [w*64, w*64+64), 16 rows/instr
#pragma unroll
      for (int j = 0; j < 4; ++j) {
        int r0 = w * 64 + j * 16;
        int row = r0 + nl4;
        int col = c0 + ((m4 ^ ((row + (row >> 2)) & 3)) << 4);
        stage16(xrow + (size_t)row * C_ + col, (char*)xs_l + r0 * 64, lane);
      }
      // stage w_hi/w_lo chunk [64co x 64c] bf16: 8 rows/instr
#pragma unroll
      for (int j = 0; j < 2; ++j) {
        int r0 = w * 16 + j * 8;
        int row = r0 + nl8;
        int col = c0 + ((m8 ^ (row & 7)) << 3);
        stage16(wrow + (size_t)row * C_ + col, (char*)whi_l + r0 * 128, lane);
        stage16(lrow + (size_t)row * C_ + col, (char*)wlo_l + r0 * 128, lane);
      }
      __syncthreads();                            // drains vmcnt (global_load_lds)
#pragma unroll
      for (int ks = 0; ks < 2; ++ks) {
        int kb = ks * 4 + quad;                   // 8-elem k-granule 0..7
        bf16x8 bx[4];
#pragma unroll
        for (int nt = 0; nt < 4; ++nt) {
          int row = w * 64 + nt * 16 + l16;
          int blk16 = (kb >> 1) ^ ((row + (row >> 2)) & 3);
          bx[nt] = cvt8(*(const u8x8*)((const char*)xs_l + row * 64 +
                                       blk16 * 16 + (kb & 1) * 8));
        }
#pragma unroll
        for (int mt = 0; mt < 4; ++mt) {
          int row = mt * 16 + l16;
          int blk = row * 8 + (kb ^ (row & 7));
          bf16x8 ah = *(const bf16x8*)((char*)whi_l + blk * 16);
          bf16x8 al = *(const bf16x8*)((char*)wlo_l + blk * 16);
#pragma unroll
          for (int nt = 0; nt < 4; ++nt) {
            acc[mt][nt] = mfma16(ah, bx[nt], acc[mt][nt]);
            acc[mt][nt] = mfma16(al, bx[nt], acc[mt][nt]);
          }
        }
      }
    }
    // epilogue: affine (no FMA contraction; /8 folded exactly) + sfa scan + store
#pragma unroll
    for (int mt = 0; mt < 4; ++mt)
#pragma unroll
      for (int r = 0; r < 4; ++r) {
        int c = co_out + mt * 16 + quad * 4 + r;
        float scv = __fmul_rn(scp[c], 0.125f);   // exact pow2 fold
        float biv = bip[c];
#pragma unroll
        for (int nt = 0; nt < 4; ++nt) {
          float y = __fmul_rn(acc[mt][nt][r], scv);
          y = __fadd_rn(y, biv);
          float u = __fadd_rn(hst[mt][nt][r], y);
          float s = quant_step(u);
          hst[mt][nt][r] = __fsub_rn(u, s);
          unsigned char sp = (unsigned char)s;
          int n = w * 64 + nt * 16 + l16;
          if (mode == 0)      q_s8[((size_t)(t * B_ + b) * N_ + n) * C_ + c] = sp;
          else if (mode == 1) k_s8[((size_t)(t * B_ + b) * C_ + c) * N_ + n] = sp;
          else                v_s8[((size_t)(t * B_ + b) * CV_ + c) * N_ + n] = sp;
        }
      }
  }
}

// ---------------- Kernel 3: attention (q·(k^T v)) + sfa, exact (unchanged) --------
__global__ __launch_bounds__(256) void k3_attn(
    const unsigned char* __restrict__ q_s8, const unsigned char* __restrict__ k_s8,
    const unsigned char* __restrict__ v_s8, unsigned char* __restrict__ a_s8) {
  __shared__ float kvbuf[64 * 68];
  int et = blockIdx.x, hh = blockIdx.y, b = blockIdx.z;
  int tid = threadIdx.x;
  int w = tid >> 6, lane = tid & 63, quad = lane >> 4, l16 = lane & 15;
  int e0 = et * 64;

  f32x4 Aacc[4][4];
#pragma unroll
  for (int mt = 0; mt < 4; ++mt)
#pragma unroll
    for (int nt = 0; nt < 4; ++nt) Aacc[mt][nt] = (f32x4){0.f, 0.f, 0.f, 0.f};

  for (int t = 0; t < T_; ++t) {
    size_t tb = (size_t)(t * B_ + b);
    f32x4 kva[4];
#pragma unroll
    for (int et2 = 0; et2 < 4; ++et2) kva[et2] = (f32x4){0.f, 0.f, 0.f, 0.f};
    const unsigned char* krow  = k_s8 + ((size_t)tb * C_ + hh * DH_ + w * 16 + l16) * N_;
    const unsigned char* vbase = v_s8 + ((size_t)tb * CV_ + hh * DV_ + e0) * N_;
    for (int kc = 0; kc < 8; ++kc) {
      int koff = kc * 32 + quad * 8;
      bf16x8 a = cvt8(*(const u8x8*)(krow + koff));
#pragma unroll
      for (int et2 = 0; et2 < 4; ++et2) {
        bf16x8 bb = cvt8(*(const u8x8*)(vbase + (size_t)(et2 * 16 + l16) * N_ + koff));
        kva[et2] = mfma16(a, bb, kva[et2]);
      }
    }
    __syncthreads();
#pragma unroll
    for (int et2 = 0; et2 < 4; ++et2)
#pragma unroll
      for (int r = 0; r < 4; ++r)
        kvbuf[(w * 16 + quad * 4 + r) * 68 + et2 * 16 + l16] = kva[et2][r];
    __syncthreads();

    const unsigned char* qrow = q_s8 + ((size_t)tb * N_ + w * 64) * C_ + hh * DH_;
    for (int kc2 = 0; kc2 < 2; ++kc2) {
      int kbase = kc2 * 32 + quad * 8;
      bf16x8 bq[4];
#pragma unroll
      for (int nt = 0; nt < 4; ++nt)
        bq[nt] = cvt8(*(const u8x8*)(qrow + (size_t)(nt * 16 + l16) * C_ + kbase));
#pragma unroll
      for (int mt = 0; mt < 4; ++mt) {
        bf16x8 ahi, alo;
#pragma unroll
        for (int j = 0; j < 8; ++j) {
          float v = kvbuf[(kbase + j) * 68 + mt * 16 + l16] * 0.015625f;
          __bf16 hi = (__bf16)v;
          ahi[j] = hi;
          alo[j] = (__bf16)(v - (float)hi);
        }
#pragma unroll
        for (int nt = 0; nt < 4; ++nt) {
          Aacc[mt][nt] = mfma16(ahi, bq[nt], Aacc[mt][nt]);
          Aacc[mt][nt] = mfma16(alo, bq[nt], Aacc[mt][nt]);
        }
      }
    }
#pragma unroll
    for (int mt = 0; mt < 4; ++mt)
#pragma unroll
      for (int nt = 0; nt < 4; ++nt)
#pragma unroll
        for (int r = 0; r < 4; ++r) {
          float u = Aacc[mt][nt][r] * 0.03125f;
          float s = quant_step(u);
          int cv = hh * DV_ + e0 + mt * 16 + quad * 4 + r;
          int n  = w * 64 + nt * 16 + l16;
          a_s8[(tb * N_ + n) * CV_ + cv] = (unsigned char)s;
          Aacc[mt][nt][r] = __fsub_rn(Aacc[mt][nt][r], 32.0f * s);
        }
  }
}

// ---------------- Kernel 4: out = conv_bn(attn spikes/8, wp), 2 tb per block ------
__global__ __launch_bounds__(256) void k4_pconv(
    const unsigned char* __restrict__ a_s8,
    const bf16_t* __restrict__ wp_hi, const bf16_t* __restrict__ wp_lo,
    const float* __restrict__ p_scale, const float* __restrict__ p_bias,
    float* __restrict__ out) {
  __shared__ __align__(16) unsigned char as_l[2][256 * 64];  // 32 KB
  __shared__ __align__(16) bf16_t whi_l[64 * 64];            //  8 KB
  __shared__ __align__(16) bf16_t wlo_l[64 * 64];            //  8 KB

  int ct  = blockIdx.x;                // 0..7 co-tile
  int tbp = blockIdx.y;                // 0..63 tb pair
  int tid = threadIdx.x;
  int w = tid >> 6, lane = tid & 63, quad = lane >> 4, l16 = lane & 15;
  int nl4 = lane >> 2, m4 = lane & 3;
  int nl8 = lane >> 3, m8 = lane & 7;
  int co0 = ct * 64;

  const unsigned char* arow0 = a_s8 + (size_t)(2 * tbp) * N_ * CV_;
  const unsigned char* arow1 = arow0 + (size_t)N_ * CV_;
  const bf16_t* wrow = wp_hi + (size_t)co0 * CV_;
  const bf16_t* lrow = wp_lo + (size_t)co0 * CV_;

  f32x4 acc[2][4][4];
#pragma unroll
  for (int tbi = 0; tbi < 2; ++tbi)
#pragma unroll
    for (int mt = 0; mt < 4; ++mt)
#pragma unroll
      for (int nt = 0; nt < 4; ++nt) acc[tbi][mt][nt] = (f32x4){0.f, 0.f, 0.f, 0.f};

  for (int kc = 0; kc < 32; ++kc) {    // K = 2048, BK = 64
    int c0 = kc * 64;
    __syncthreads();
#pragma unroll
    for (int j = 0; j < 4; ++j) {
      int r0 = w * 64 + j * 16;
      int row = r0 + nl4;
      int col = c0 + ((m4 ^ ((row + (row >> 2)) & 3)) << 4);
      stage16(arow0 + (size_t)row * CV_ + col, (char*)as_l[0] + r0 * 64, lane);
      stage16(arow1 + (size_t)row * CV_ + col, (char*)as_l[1] + r0 * 64, lane);
    }
#pragma unroll
    for (int j = 0; j < 2; ++j) {
      int r0 = w * 16 + j * 8;
      int row = r0 + nl8;
      int col = c0 + ((m8 ^ (row & 7)) << 3);
      stage16(wrow + (size_t)row * CV_ + col, (char*)whi_l + r0 * 128, lane);
      stage16(lrow + (size_t)row * CV_ + col, (char*)wlo_l + r0 * 128, lane);
    }
    __syncthreads();
#pragma unroll
    for (int ks = 0; ks < 2; ++ks) {
      int kb = ks * 4 + quad;
      bf16x8 ba[2][4];
#pragma unroll
      for (int tbi = 0; tbi < 2; ++tbi)
#pragma unroll
        for (int nt = 0; nt < 4; ++nt) {
          int row = w * 64 + nt * 16 + l16;
          int blk16 = (kb >> 1) ^ ((row + (row >> 2)) & 3);
          ba[tbi][nt] = cvt8(*(const u8x8*)((const char*)as_l[tbi] + row * 64 +
                                            blk16 * 16 + (kb & 1) * 8));
        }
#pragma unroll
      for (int mt = 0; mt < 4; ++mt) {
        int row = mt * 16 + l16;
        int blk = row * 8 + (kb ^ (row & 7));
        bf16x8 ah = *(const bf16x8*)((char*)whi_l + blk * 16);
        bf16x8 al = *(const bf16x8*)((char*)wlo_l + blk * 16);
#pragma unroll
        for (int tbi = 0; tbi < 2; ++tbi)
#pragma unroll
          for (int nt = 0; nt < 4; ++nt) {
            acc[tbi][mt][nt] = mfma16(ah, ba[tbi][nt], acc[tbi][mt][nt]);
            acc[tbi][mt][nt] = mfma16(al, ba[tbi][nt], acc[tbi][mt][nt]);
          }
      }
    }
  }
#pragma unroll
  for (int mt = 0; mt < 4; ++mt)
#pragma unroll
    for (int r = 0; r < 4; ++r) {
      int c = co0 + mt * 16 + quad * 4 + r;
      float scv = __fmul_rn(p_scale[c], 0.125f);  // exact pow2 fold
      float biv = p_bias[c];
#pragma unroll
      for (int tbi = 0; tbi < 2; ++tbi)
#pragma unroll
        for (int nt = 0; nt < 4; ++nt) {
          float y = __fmul_rn(acc[tbi][mt][nt][r], scv);
          y = __fadd_rn(y, biv);
          int n = w * 64 + nt * 16 + l16;
          out[((size_t)(2 * tbp + tbi) * C_ + c) * N_ + n] = y;
        }
    }
}

extern "C" void kernel_launch(void* const* d_in, const int* in_sizes, int n_in,
                              void* d_out, int out_size, void* d_ws, size_t ws_size,
                              hipStream_t stream) {
  const float* x       = (const float*)d_in[0];
  const float* wq      = (const float*)d_in[1];
  const float* wk      = (const float*)d_in[2];
  const float* wv      = (const float*)d_in[3];
  const float* wp      = (const float*)d_in[4];
  const float* q_scale = (const float*)d_in[5];
  const float* q_bias  = (const float*)d_in[6];
  const float* k_scale = (const float*)d_in[7];
  const float* k_bias  = (const float*)d_in[8];
  const float* v_scale = (const float*)d_in[9];
  const float* v_bias  = (const float*)d_in[10];
  const float* p_scale = (const float*)d_in[11];
  const float* p_bias  = (const float*)d_in[12];

  // workspace (160 MiB), time-multiplexed:
  //  [0,16M)   xsT u8 [T,B,N,C]       (K1 out, K2 in; dead after K2)
  //  [32,38M)  w_qkv hi|lo bf16       (k0 out, K2 in; dead after K2)
  //  [0,64M)   a_s8 [T,B,N,CV]        (K3 out, K4 in) -- clobbers the two above
  //  [64,80M)  q_s8 [T,B,N,C]         (K2 out, K3 in; dead after K3)
  //  [64,66M)+[66,68M) wp hi|lo       (k0p out after K3, K4 in)
  //  [80,96M)  k_s8 [T,B,C,N]
  //  [96,160M) v_s8 [T,B,CV,N]
  const size_t MB = 1024 * 1024;
  if (ws_size < 160 * MB) return;
  char* ws = (char*)d_ws;
  unsigned char* xsT    = (unsigned char*)(ws);
  unsigned char* a_s8   = (unsigned char*)(ws);
  bf16_t*        wqkv_h = (bf16_t*)(ws + 32 * MB);
  bf16_t*        wqkv_l = (bf16_t*)(ws + 35 * MB);
  unsigned char* q_s8   = (unsigned char*)(ws + 64 * MB);
  bf16_t*        wp_h   = (bf16_t*)(ws + 64 * MB);
  bf16_t*        wp_l   = (bf16_t*)(ws + 66 * MB);
  unsigned char* k_s8   = (unsigned char*)(ws + 80 * MB);
  unsigned char* v_s8   = (unsigned char*)(ws + 96 * MB);

  // weight splits: combined rows [wq | wk | wv] of length C_
  k0_split<<<128, 256, 0, stream>>>(wq, wqkv_h, wqkv_l, 32768);
  k0_split<<<128, 256, 0, stream>>>(wk, wqkv_h + 262144, wqkv_l + 262144, 32768);
  k0_split<<<512, 256, 0, stream>>>(wv, wqkv_h + 524288, wqkv_l + 524288, 131072);

  k1_sfa_x<<<dim3(32, B_), 256, 0, stream>>>(x, xsT);
  k2_qkv<<<dim3(48, B_), 256, 0, stream>>>(xsT, wqkv_h, wqkv_l,
                                           q_scale, q_bias, k_scale, k_bias,
                                           v_scale, v_bias, q_s8, k_s8, v_s8);
  k3_attn<<<dim3(4, NH_, B_), 256, 0, stream>>>(q_s8, k_s8, v_s8, a_s8);
  k0_split<<<512, 256, 0, stream>>>(wp, wp_h, wp_l, 131072);   // q_s8 dead now
  k4_pconv<<<dim3(8, 64), 256, 0, stream>>>(a_s8, wp_h, wp_l,
                                            p_scale, p_bias, (float*)d_out);
}

// Round 7
// 587.949 us; speedup vs baseline: 1.5132x; 1.5132x over previous
//
#include <hip/hip_runtime.h>
#include <hip/hip_bf16.h>

#define T_  4
#define B_  32
#define C_  512
#define CV_ 2048
#define N_  256
#define NH_ 8
#define DH_ 64
#define DV_ 256

typedef __bf16 bf16_t;
typedef __bf16 bf16x8 __attribute__((ext_vector_type(8)));
typedef float  f32x4  __attribute__((ext_vector_type(4)));
typedef unsigned char u8x8 __attribute__((ext_vector_type(8)));

#if defined(__has_builtin)
# if __has_builtin(__builtin_amdgcn_global_load_lds)
#  define USE_GLL 1
# endif
#endif

__device__ __forceinline__ f32x4 mfma16(bf16x8 a, bf16x8 b, f32x4 c) {
  return __builtin_amdgcn_mfma_f32_16x16x32_bf16(a, b, c, 0, 0, 0);
}

// s = round(clip(u,0,8)); rintf = round-half-even, matching jnp.round/np.round
__device__ __forceinline__ float quant_step(float u) {
  return rintf(fminf(fmaxf(u, 0.0f), 8.0f));
}

// uchar8 (spike ints 0..8) -> bf16x8 exact integer values
__device__ __forceinline__ bf16x8 cvt8(u8x8 v) {
  bf16x8 r;
#pragma unroll
  for (int j = 0; j < 8; ++j) r[j] = (bf16_t)(float)(unsigned int)v[j];
  return r;
}

// Async 16B/lane global->LDS stage; lbase wave-uniform, HW dest = lbase+lane*16.
__device__ __forceinline__ void stage16(const void* g, void* lbase, int lane) {
#ifdef USE_GLL
  __builtin_amdgcn_global_load_lds(
      (const __attribute__((address_space(1))) void*)g,
      (__attribute__((address_space(3))) void*)lbase, 16, 0, 0);
#else
  *(uint4*)((char*)lbase + lane * 16) = *(const uint4*)g;
#endif
}

// ---------------- Kernel 0: split f32 weights into bf16 hi + lo ----------------
__global__ __launch_bounds__(256) void k0_split(const float* __restrict__ src,
                                                bf16_t* __restrict__ hi,
                                                bf16_t* __restrict__ lo, int n8) {
  int i = blockIdx.x * 256 + threadIdx.x;
  if (i >= n8) return;
  const float* s = src + (size_t)i * 8;
  bf16x8 h, l;
#pragma unroll
  for (int j = 0; j < 8; ++j) {
    float w = s[j];
    __bf16 hh = (__bf16)w;
    h[j] = hh;
    l[j] = (__bf16)(w - (float)hh);   // near-exact residual
  }
  *(bf16x8*)(hi + (size_t)i * 8) = h;
  *(bf16x8*)(lo + (size_t)i * 8) = l;
}

// ---------------- Kernel 1: xs = sfa(x) -> xsT [t,b,n,c] u8 spike ints ------------
__global__ __launch_bounds__(256) void k1_sfa_x(const float* __restrict__ x,
                                                unsigned char* __restrict__ xsT) {
  __shared__ unsigned char tile[64 * 80];        // [n][c], pad 80
  int bt = blockIdx.x;                            // c-tile = bt>>2, n-tile = bt&3
  int b  = blockIdx.y;
  int tid = threadIdx.x;
  int c0 = (bt >> 2) * 64, n0 = (bt & 3) * 64;
  int cl = tid >> 2, nc = (tid & 3) * 16;        // reader role
  int nl = tid >> 2, cj = (tid & 3) * 16;        // writer role

  float h[16];
#pragma unroll
  for (int j = 0; j < 16; ++j) h[j] = 0.0f;

  for (int t = 0; t < T_; ++t) {
    const float* xp = x + ((size_t)(t * B_ + b) * C_ + c0 + cl) * N_ + n0 + nc;
    f32x4 xv[4];
#pragma unroll
    for (int j = 0; j < 4; ++j) xv[j] = *(const f32x4*)(xp + j * 4);
    if (t) __syncthreads();
#pragma unroll
    for (int j = 0; j < 16; ++j) {
      float u = __fadd_rn(h[j], xv[j >> 2][j & 3]);  // reference scan op order
      float s = quant_step(u);
      h[j] = __fsub_rn(u, s);                    // exact
      tile[(nc + j) * 80 + cl] = (unsigned char)s;
    }
    __syncthreads();
    uint4 o = *(const uint4*)&tile[nl * 80 + cj];
    *(uint4*)(xsT + ((size_t)(t * B_ + b) * N_ + n0 + nl) * C_ + c0 + cj) = o;
  }
}

// ---------------- Kernel 2: q|k|v = sfa(conv_bn(xs, W)) ---------------------------
// Block: 64 co x 64 n x ALL 4 t (t lives in the accumulator; scan runs entirely in
// the epilogue -> no persistent scan-state VGPRs -> 3 blocks/CU). Weights staged
// once per K-chunk, shared across the 4 t. SWAPQ: q-mode swaps MFMA operands so the
// D-fragment is [n][c] -> coalesced q stores.
template<bool SWAPQ>
__global__ __launch_bounds__(256, 3) void k2_qkv(
    const unsigned char* __restrict__ xsT,
    const bf16_t* __restrict__ w_hi, const bf16_t* __restrict__ w_lo,
    const float* __restrict__ q_scale, const float* __restrict__ q_bias,
    const float* __restrict__ k_scale, const float* __restrict__ k_bias,
    const float* __restrict__ v_scale, const float* __restrict__ v_bias,
    unsigned char* __restrict__ q_s8, unsigned char* __restrict__ k_s8,
    unsigned char* __restrict__ v_s8, int ct_off) {
  __shared__ __align__(16) unsigned char xs_l[T_][4][1024];  // 16 KB [t][wave][16n x 64c]
  __shared__ __align__(16) bf16_t whi_l[64 * 64];            //  8 KB
  __shared__ __align__(16) bf16_t wlo_l[64 * 64];            //  8 KB

  int ct = blockIdx.x + ct_off;
  int ntile = blockIdx.y, b = blockIdx.z;
  int tid = threadIdx.x;
  int w = tid >> 6, lane = tid & 63, quad = lane >> 4, l16 = lane & 15;

  int mode, co_out;
  const float *scp, *bip;
  if (ct < 8)       { mode = 0; co_out = ct * 64;        scp = q_scale; bip = q_bias; }
  else if (ct < 16) { mode = 1; co_out = (ct - 8) * 64;  scp = k_scale; bip = k_bias; }
  else              { mode = 2; co_out = (ct - 16) * 64; scp = v_scale; bip = v_bias; }

  const bf16_t* wrow = w_hi + (size_t)ct * 64 * C_;
  const bf16_t* lrow = w_lo + (size_t)ct * 64 * C_;
  int n0b = ntile * 64;

  int r4 = lane >> 2, m4 = lane & 3;             // u8 staging roles
  int sw4 = (r4 + (r4 >> 2)) & 3;
  int r8 = lane >> 3, m8 = lane & 7;             // bf16 staging roles

  f32x4 acc[T_][4];                              // [t][mt]
#pragma unroll
  for (int t = 0; t < T_; ++t)
#pragma unroll
    for (int mt = 0; mt < 4; ++mt) acc[t][mt] = (f32x4){0.f, 0.f, 0.f, 0.f};

  for (int kc = 0; kc < 8; ++kc) {               // K = 512, BK = 64
    int c0 = kc * 64;
    __syncthreads();
    // stage xs: one instr per t (wave's own 16 n-rows)
#pragma unroll
    for (int t = 0; t < T_; ++t) {
      const unsigned char* g = xsT +
          ((size_t)(t * B_ + b) * N_ + n0b + w * 16 + r4) * C_ + c0 + ((m4 ^ sw4) << 4);
      stage16(g, &xs_l[t][w][0], lane);
    }
    // stage w hi/lo: 2+2 instr per wave
#pragma unroll
    for (int j = 0; j < 2; ++j) {
      int r0 = w * 16 + j * 8;
      int row = r0 + r8;
      int col = c0 + ((m8 ^ (row & 7)) << 3);
      stage16(wrow + (size_t)row * C_ + col, (char*)whi_l + r0 * 128, lane);
      stage16(lrow + (size_t)row * C_ + col, (char*)wlo_l + r0 * 128, lane);
    }
    __syncthreads();
#pragma unroll
    for (int ks = 0; ks < 2; ++ks) {
      int kb = ks * 4 + quad;                    // 8-elem k-granule 0..7
      int slot = (kb >> 1) ^ ((l16 + (l16 >> 2)) & 3);
      int xoff = l16 * 64 + slot * 16 + (kb & 1) * 8;
      bf16x8 bx[T_];
#pragma unroll
      for (int t = 0; t < T_; ++t)
        bx[t] = cvt8(*(const u8x8*)((const char*)&xs_l[t][w][0] + xoff));
#pragma unroll
      for (int mt = 0; mt < 4; ++mt) {
        int row = mt * 16 + l16;
        int woff = row * 128 + ((kb ^ (row & 7)) << 4);
        bf16x8 ah = *(const bf16x8*)((const char*)whi_l + woff);
        bf16x8 al = *(const bf16x8*)((const char*)wlo_l + woff);
#pragma unroll
        for (int t = 0; t < T_; ++t) {
          if (SWAPQ) {
            acc[t][mt] = mfma16(bx[t], ah, acc[t][mt]);
            acc[t][mt] = mfma16(bx[t], al, acc[t][mt]);
          } else {
            acc[t][mt] = mfma16(ah, bx[t], acc[t][mt]);
            acc[t][mt] = mfma16(al, bx[t], acc[t][mt]);
          }
        }
      }
    }
  }
  // epilogue: affine (no FMA contraction; /8 folded exactly) + t-scan + u8 store
  if (SWAPQ) {
    float sc[4], bi[4], h[4][4];
#pragma unroll
    for (int mt = 0; mt < 4; ++mt) {
      int c = co_out + mt * 16 + l16;
      sc[mt] = __fmul_rn(q_scale[c], 0.125f);    // exact pow2 fold
      bi[mt] = q_bias[c];
#pragma unroll
      for (int r = 0; r < 4; ++r) h[mt][r] = 0.0f;
    }
#pragma unroll
    for (int t = 0; t < T_; ++t)
#pragma unroll
      for (int mt = 0; mt < 4; ++mt)
#pragma unroll
        for (int r = 0; r < 4; ++r) {
          float y = __fmul_rn(acc[t][mt][r], sc[mt]);
          y = __fadd_rn(y, bi[mt]);
          float u = __fadd_rn(h[mt][r], y);
          float s = quant_step(u);
          h[mt][r] = __fsub_rn(u, s);
          int n = n0b + w * 16 + quad * 4 + r;
          int c = co_out + mt * 16 + l16;
          q_s8[((size_t)(t * B_ + b) * N_ + n) * C_ + c] = (unsigned char)s;
        }
  } else {
    float sc[4][4], bi[4][4], h[4][4];
#pragma unroll
    for (int mt = 0; mt < 4; ++mt)
#pragma unroll
      for (int r = 0; r < 4; ++r) {
        int c = co_out + mt * 16 + quad * 4 + r;
        sc[mt][r] = __fmul_rn(scp[c], 0.125f);
        bi[mt][r] = bip[c];
        h[mt][r] = 0.0f;
      }
#pragma unroll
    for (int t = 0; t < T_; ++t)
#pragma unroll
      for (int mt = 0; mt < 4; ++mt)
#pragma unroll
        for (int r = 0; r < 4; ++r) {
          float y = __fmul_rn(acc[t][mt][r], sc[mt][r]);
          y = __fadd_rn(y, bi[mt][r]);
          float u = __fadd_rn(h[mt][r], y);
          float s = quant_step(u);
          h[mt][r] = __fsub_rn(u, s);
          int n = n0b + w * 16 + l16;
          int c = co_out + mt * 16 + quad * 4 + r;
          unsigned char sp = (unsigned char)s;
          if (mode == 1) k_s8[((size_t)(t * B_ + b) * C_ + c) * N_ + n] = sp;
          else           v_s8[((size_t)(t * B_ + b) * CV_ + c) * N_ + n] = sp;
        }
  }
}

// ---------------- Kernel 3: attention (q·(k^T v)) + sfa, exact --------------------
__global__ __launch_bounds__(256) void k3_attn(
    const unsigned char* __restrict__ q_s8, const unsigned char* __restrict__ k_s8,
    const unsigned char* __restrict__ v_s8, unsigned char* __restrict__ a_s8) {
  __shared__ float kvbuf[64 * 68];
  int et = blockIdx.x, hh = blockIdx.y, b = blockIdx.z;
  int tid = threadIdx.x;
  int w = tid >> 6, lane = tid & 63, quad = lane >> 4, l16 = lane & 15;
  int e0 = et * 64;

  f32x4 Aacc[4][4];
#pragma unroll
  for (int mt = 0; mt < 4; ++mt)
#pragma unroll
    for (int nt = 0; nt < 4; ++nt) Aacc[mt][nt] = (f32x4){0.f, 0.f, 0.f, 0.f};

  for (int t = 0; t < T_; ++t) {
    size_t tb = (size_t)(t * B_ + b);
    f32x4 kva[4];
#pragma unroll
    for (int et2 = 0; et2 < 4; ++et2) kva[et2] = (f32x4){0.f, 0.f, 0.f, 0.f};
    const unsigned char* krow  = k_s8 + ((size_t)tb * C_ + hh * DH_ + w * 16 + l16) * N_;
    const unsigned char* vbase = v_s8 + ((size_t)tb * CV_ + hh * DV_ + e0) * N_;
    for (int kc = 0; kc < 8; ++kc) {
      int koff = kc * 32 + quad * 8;
      bf16x8 a = cvt8(*(const u8x8*)(krow + koff));
#pragma unroll
      for (int et2 = 0; et2 < 4; ++et2) {
        bf16x8 bb = cvt8(*(const u8x8*)(vbase + (size_t)(et2 * 16 + l16) * N_ + koff));
        kva[et2] = mfma16(a, bb, kva[et2]);
      }
    }
    __syncthreads();
#pragma unroll
    for (int et2 = 0; et2 < 4; ++et2)
#pragma unroll
      for (int r = 0; r < 4; ++r)
        kvbuf[(w * 16 + quad * 4 + r) * 68 + et2 * 16 + l16] = kva[et2][r];
    __syncthreads();

    const unsigned char* qrow = q_s8 + ((size_t)tb * N_ + w * 64) * C_ + hh * DH_;
    for (int kc2 = 0; kc2 < 2; ++kc2) {
      int kbase = kc2 * 32 + quad * 8;
      bf16x8 bq[4];
#pragma unroll
      for (int nt = 0; nt < 4; ++nt)
        bq[nt] = cvt8(*(const u8x8*)(qrow + (size_t)(nt * 16 + l16) * C_ + kbase));
#pragma unroll
      for (int mt = 0; mt < 4; ++mt) {
        bf16x8 ahi, alo;
#pragma unroll
        for (int j = 0; j < 8; ++j) {
          float v = kvbuf[(kbase + j) * 68 + mt * 16 + l16] * 0.015625f;
          __bf16 hi = (__bf16)v;
          ahi[j] = hi;
          alo[j] = (__bf16)(v - (float)hi);
        }
#pragma unroll
        for (int nt = 0; nt < 4; ++nt) {
          Aacc[mt][nt] = mfma16(ahi, bq[nt], Aacc[mt][nt]);
          Aacc[mt][nt] = mfma16(alo, bq[nt], Aacc[mt][nt]);
        }
      }
    }
#pragma unroll
    for (int mt = 0; mt < 4; ++mt)
#pragma unroll
      for (int nt = 0; nt < 4; ++nt)
#pragma unroll
        for (int r = 0; r < 4; ++r) {
          float u = Aacc[mt][nt][r] * 0.03125f;
          float s = quant_step(u);
          int cv = hh * DV_ + e0 + mt * 16 + quad * 4 + r;
          int n  = w * 64 + nt * 16 + l16;
          a_s8[(tb * N_ + n) * CV_ + cv] = (unsigned char)s;
          Aacc[mt][nt][r] = __fsub_rn(Aacc[mt][nt][r], 32.0f * s);
        }
  }
}

// ---------------- Kernel 4: out = conv_bn(attn spikes/8, wp) ----------------------
// Same structure as K2: 64 co x 64 n x 4 tb in the accumulator; weights staged once
// per K-chunk shared across 4 tb. 3 blocks/CU.
__global__ __launch_bounds__(256, 3) void k4_pconv(
    const unsigned char* __restrict__ a_s8,
    const bf16_t* __restrict__ wp_hi, const bf16_t* __restrict__ wp_lo,
    const float* __restrict__ p_scale, const float* __restrict__ p_bias,
    float* __restrict__ out) {
  __shared__ __align__(16) unsigned char as_l[4][4][1024];   // 16 KB [tbi][wave][16n x 64c]
  __shared__ __align__(16) bf16_t whi_l[64 * 64];            //  8 KB
  __shared__ __align__(16) bf16_t wlo_l[64 * 64];            //  8 KB

  int ct = blockIdx.x, ntile = blockIdx.y, tbq = blockIdx.z;
  int tid = threadIdx.x;
  int w = tid >> 6, lane = tid & 63, quad = lane >> 4, l16 = lane & 15;
  int co0 = ct * 64, n0b = ntile * 64;

  int r4 = lane >> 2, m4 = lane & 3;
  int sw4 = (r4 + (r4 >> 2)) & 3;
  int r8 = lane >> 3, m8 = lane & 7;

  const bf16_t* wrow = wp_hi + (size_t)co0 * CV_;
  const bf16_t* lrow = wp_lo + (size_t)co0 * CV_;

  f32x4 acc[4][4];                               // [tbi][mt]
#pragma unroll
  for (int i = 0; i < 4; ++i)
#pragma unroll
    for (int mt = 0; mt < 4; ++mt) acc[i][mt] = (f32x4){0.f, 0.f, 0.f, 0.f};

  for (int kc = 0; kc < 32; ++kc) {              // K = 2048, BK = 64
    int c0 = kc * 64;
    __syncthreads();
#pragma unroll
    for (int tbi = 0; tbi < 4; ++tbi) {
      const unsigned char* g = a_s8 +
          ((size_t)(tbq * 4 + tbi) * N_ + n0b + w * 16 + r4) * CV_ + c0 + ((m4 ^ sw4) << 4);
      stage16(g, &as_l[tbi][w][0], lane);
    }
#pragma unroll
    for (int j = 0; j < 2; ++j) {
      int r0 = w * 16 + j * 8;
      int row = r0 + r8;
      int col = c0 + ((m8 ^ (row & 7)) << 3);
      stage16(wrow + (size_t)row * CV_ + col, (char*)whi_l + r0 * 128, lane);
      stage16(lrow + (size_t)row * CV_ + col, (char*)wlo_l + r0 * 128, lane);
    }
    __syncthreads();
#pragma unroll
    for (int ks = 0; ks < 2; ++ks) {
      int kb = ks * 4 + quad;
      int slot = (kb >> 1) ^ ((l16 + (l16 >> 2)) & 3);
      int xoff = l16 * 64 + slot * 16 + (kb & 1) * 8;
      bf16x8 bx[4];
#pragma unroll
      for (int tbi = 0; tbi < 4; ++tbi)
        bx[tbi] = cvt8(*(const u8x8*)((const char*)&as_l[tbi][w][0] + xoff));
#pragma unroll
      for (int mt = 0; mt < 4; ++mt) {
        int row = mt * 16 + l16;
        int woff = row * 128 + ((kb ^ (row & 7)) << 4);
        bf16x8 ah = *(const bf16x8*)((const char*)whi_l + woff);
        bf16x8 al = *(const bf16x8*)((const char*)wlo_l + woff);
#pragma unroll
        for (int tbi = 0; tbi < 4; ++tbi) {
          acc[tbi][mt] = mfma16(ah, bx[tbi], acc[tbi][mt]);
          acc[tbi][mt] = mfma16(al, bx[tbi], acc[tbi][mt]);
        }
      }
    }
  }
#pragma unroll
  for (int mt = 0; mt < 4; ++mt)
#pragma unroll
    for (int r = 0; r < 4; ++r) {
      int c = co0 + mt * 16 + quad * 4 + r;
      float scv = __fmul_rn(p_scale[c], 0.125f);  // exact pow2 fold
      float biv = p_bias[c];
#pragma unroll
      for (int tbi = 0; tbi < 4; ++tbi) {
        float y = __fmul_rn(acc[tbi][mt][r], scv);
        y = __fadd_rn(y, biv);
        int n = n0b + w * 16 + l16;
        out[((size_t)(tbq * 4 + tbi) * C_ + c) * N_ + n] = y;
      }
    }
}

extern "C" void kernel_launch(void* const* d_in, const int* in_sizes, int n_in,
                              void* d_out, int out_size, void* d_ws, size_t ws_size,
                              hipStream_t stream) {
  const float* x       = (const float*)d_in[0];
  const float* wq      = (const float*)d_in[1];
  const float* wk      = (const float*)d_in[2];
  const float* wv      = (const float*)d_in[3];
  const float* wp      = (const float*)d_in[4];
  const float* q_scale = (const float*)d_in[5];
  const float* q_bias  = (const float*)d_in[6];
  const float* k_scale = (const float*)d_in[7];
  const float* k_bias  = (const float*)d_in[8];
  const float* v_scale = (const float*)d_in[9];
  const float* v_bias  = (const float*)d_in[10];
  const float* p_scale = (const float*)d_in[11];
  const float* p_bias  = (const float*)d_in[12];

  // workspace (160 MiB), time-multiplexed:
  //  [0,16M)   xsT u8 [T,B,N,C]       (K1 out, K2 in; dead after K2)
  //  [32,38M)  w_qkv hi|lo bf16       (k0 out, K2 in; dead after K2)
  //  [0,64M)   a_s8 [T,B,N,CV]        (K3 out, K4 in) -- clobbers the two above
  //  [64,80M)  q_s8 [T,B,N,C]         (K2 out, K3 in; dead after K3)
  //  [64,66M)+[66,68M) wp hi|lo       (k0p out after K3, K4 in)
  //  [80,96M)  k_s8 [T,B,C,N]
  //  [96,160M) v_s8 [T,B,CV,N]
  const size_t MB = 1024 * 1024;
  if (ws_size < 160 * MB) return;
  char* ws = (char*)d_ws;
  unsigned char* xsT    = (unsigned char*)(ws);
  unsigned char* a_s8   = (unsigned char*)(ws);
  bf16_t*        wqkv_h = (bf16_t*)(ws + 32 * MB);
  bf16_t*        wqkv_l = (bf16_t*)(ws + 35 * MB);
  unsigned char* q_s8   = (unsigned char*)(ws + 64 * MB);
  bf16_t*        wp_h   = (bf16_t*)(ws + 64 * MB);
  bf16_t*        wp_l   = (bf16_t*)(ws + 66 * MB);
  unsigned char* k_s8   = (unsigned char*)(ws + 80 * MB);
  unsigned char* v_s8   = (unsigned char*)(ws + 96 * MB);

  // weight splits: combined rows [wq | wk | wv] of length C_
  k0_split<<<128, 256, 0, stream>>>(wq, wqkv_h, wqkv_l, 32768);
  k0_split<<<128, 256, 0, stream>>>(wk, wqkv_h + 262144, wqkv_l + 262144, 32768);
  k0_split<<<512, 256, 0, stream>>>(wv, wqkv_h + 524288, wqkv_l + 524288, 131072);

  k1_sfa_x<<<dim3(32, B_), 256, 0, stream>>>(x, xsT);
  k2_qkv<true><<<dim3(8, 4, B_), 256, 0, stream>>>(
      xsT, wqkv_h, wqkv_l, q_scale, q_bias, k_scale, k_bias,
      v_scale, v_bias, q_s8, k_s8, v_s8, 0);
  k2_qkv<false><<<dim3(40, 4, B_), 256, 0, stream>>>(
      xsT, wqkv_h, wqkv_l, q_scale, q_bias, k_scale, k_bias,
      v_scale, v_bias, q_s8, k_s8, v_s8, 8);
  k3_attn<<<dim3(4, NH_, B_), 256, 0, stream>>>(q_s8, k_s8, v_s8, a_s8);
  k0_split<<<512, 256, 0, stream>>>(wp, wp_h, wp_l, 131072);   // q_s8 dead now
  k4_pconv<<<dim3(8, 4, B_), 256, 0, stream>>>(a_s8, wp_h, wp_l,
                                               p_scale, p_bias, (float*)d_out);
}